// Round 9
// baseline (151.540 us; speedup 1.0000x reference)
//
#include <hip/hip_runtime.h>

#define SEQ   2048
#define NBATCH 8
#define EMB   1024
#define HD    64
#define QKVSZ (NBATCH * SEQ * HD)   /* 1048576 elems per matrix */
#define WTSZ  (3 * HD * EMB)        /* 196608 */
#define PSLOT2 4224                 /* 64*64 O + 64 m + 64 l */

typedef __attribute__((ext_vector_type(8))) short bf16x8;
typedef __attribute__((ext_vector_type(4))) float f32x4;

__device__ inline unsigned short f2b(float f) {
  union { float f; unsigned int i; } u; u.f = f;
  unsigned int r = (u.i + 0x7FFFu + ((u.i >> 16) & 1u)) >> 16;  // RNE
  return (unsigned short)r;
}

// Direct global->LDS DMA, 16B per lane. LDS dest = uniform base + lane*16 (linear);
// swizzle is applied on the per-lane GLOBAL source address (inverse), read-side keeps XOR.
#define GLOAD_LDS16(g, l)                                              \
  __builtin_amdgcn_global_load_lds(                                    \
      (const __attribute__((address_space(1))) void*)(g),              \
      (__attribute__((address_space(3))) void*)(l), 16, 0, 0)

// ---------------- W transpose -> K-blocked layout [kb][m][c][kd] ----------------
__global__ __launch_bounds__(256) void wtrans_kernel(const float* __restrict__ wq,
                                                     const float* __restrict__ wk,
                                                     const float* __restrict__ wv,
                                                     unsigned short* __restrict__ wt) {
  int i = blockIdx.x * 256 + threadIdx.x;       // 0 .. 196607
  int kb  = i / 12288;
  int rem = i - kb * 12288;
  int m   = rem >> 12;          // 0..2
  int c   = (rem >> 6) & 63;    // output col within head
  int kd  = rem & 63;           // k within block
  const float* src = (m == 0) ? wq : ((m == 1) ? wk : wv);
  int d = kb * 64 + kd;
  wt[i] = f2b(src[d * 64 + c]);
}

// ---------------- QKV projection: register-blocked 32x64 wave-tiles ----------------
// BM=32, BN=192 (all Q,K,V cols in one block -> A read ONCE). 3 waves/block (192 thr),
// wave wc owns matrix wc (64 cols) as a 2x4 grid of 16x16x32 fragments.
// Per wave per K-step: 12 ds_read_b128 for 16 MFMA (was 8 for 6) -> 1.8x less LDS traffic.
// grid = 512 -> 2 blocks/CU (LDS 56 KB); W via global_load_lds, A reg-staged (f2b).
__global__ __launch_bounds__(192) void qkv_proj_kernel(const float* __restrict__ emb,
                                                       const unsigned short* __restrict__ wt,
                                                       unsigned short* __restrict__ qkv) {
  __shared__ __align__(16) unsigned short Ab[2][32 * 64];    // 8 KB  (swizzled via staged writes)
  __shared__ __align__(16) unsigned short Wb[2][192 * 64];   // 48 KB (linear dest, src pre-swizzled)

  const int t    = threadIdx.x;
  const int wave = t >> 6;          // 0..2 == matrix index (Q,K,V)
  const int lane = t & 63;
  const int quad = lane >> 4;
  const int l16  = lane & 15;
  const int rt   = blockIdx.x;      // 32-row tile, 0..511

  const float* aBase = emb + (size_t)rt * 32 * EMB;
  const char*  wBase = (const char*)wt;     // chunk kb at byte kb*24576; row = m*64+c

  // per-thread pre-swizzled W source byte offsets (8 DMA instrs per wave = full 24 KB chunk)
  int wsrc[8];
#pragma unroll
  for (int i = 0; i < 8; i++) {
    int u = (wave * 8 + i) * 64 + lane;     // 0..1535 16B-units
    int row = u >> 3, k8 = u & 7;
    wsrc[i] = row * 128 + ((k8 ^ (row & 7)) << 4);
  }

  f32x4 acc[2][4];
#pragma unroll
  for (int a = 0; a < 2; a++)
#pragma unroll
    for (int n = 0; n < 4; n++) acc[a][n] = (f32x4){0.f, 0.f, 0.f, 0.f};
  f32x4 pa[3];

#define QKVA_ISSUE(kb)                                                              \
  do {                                                                              \
    _Pragma("unroll") for (int j = 0; j < 3; j++) {                                 \
      int u = t + j * 192;                                                          \
      if (j < 2 || t < 128)                                                         \
        pa[j] = *(const f32x4*)(aBase + (size_t)(u >> 4) * EMB + (kb) * 64 + (u & 15) * 4); \
    }                                                                               \
  } while (0)

#define QKVW_DMA(kb, buf)                                                           \
  do {                                                                              \
    _Pragma("unroll") for (int i = 0; i < 8; i++)                                   \
      GLOAD_LDS16(wBase + (size_t)(kb) * 24576 + wsrc[i],                           \
                  (char*)&Wb[buf][0] + (wave * 8 + i) * 1024);                      \
  } while (0)

#define QKVA_STAGE(buf)                                                             \
  do {                                                                              \
    _Pragma("unroll") for (int j = 0; j < 3; j++) {                                 \
      int u = t + j * 192;                                                          \
      if (j < 2 || t < 128) {                                                       \
        int row = u >> 4, kq = u & 15;                                              \
        unsigned int lo = (unsigned int)f2b(pa[j][0]) | ((unsigned int)f2b(pa[j][1]) << 16); \
        unsigned int hi = (unsigned int)f2b(pa[j][2]) | ((unsigned int)f2b(pa[j][3]) << 16); \
        uint2 pk; pk.x = lo; pk.y = hi;                                             \
        *(uint2*)((char*)&Ab[buf][0] + row * 128 + ((kq * 8) ^ ((row & 7) << 4))) = pk; \
      }                                                                             \
    }                                                                               \
  } while (0)

#define QKV_COMPUTE(buf)                                                            \
  do {                                                                              \
    _Pragma("unroll") for (int kh = 0; kh < 2; kh++) {                              \
      bf16x8 af[2];                                                                 \
      _Pragma("unroll") for (int a = 0; a < 2; a++) {                               \
        int arow = a * 16 + l16;                                                    \
        af[a] = *(const bf16x8*)((const char*)&Ab[buf][0] + arow * 128 +            \
                                 ((kh * 64 + quad * 16) ^ ((arow & 7) << 4)));      \
      }                                                                             \
      _Pragma("unroll") for (int nt = 0; nt < 4; nt++) {                            \
        int wrow = wave * 64 + nt * 16 + l16;                                       \
        bf16x8 wf = *(const bf16x8*)((const char*)&Wb[buf][0] + wrow * 128 +        \
                                     ((kh * 64 + quad * 16) ^ ((wrow & 7) << 4)));  \
        _Pragma("unroll") for (int a = 0; a < 2; a++)                               \
          acc[a][nt] = __builtin_amdgcn_mfma_f32_16x16x32_bf16(af[a], wf, acc[a][nt], 0, 0, 0); \
      }                                                                             \
    }                                                                               \
  } while (0)

  // ---- prologue ----
  QKVA_ISSUE(0);
  QKVW_DMA(0, 0);
  QKVA_STAGE(0);
  __syncthreads();

  // ---- main loop over 16 K-steps ----
  for (int kb = 0; kb < 16; kb++) {
    const int cur = kb & 1;
    const int nb  = cur ^ 1;
    if (kb < 15) {
      QKVA_ISSUE(kb + 1);        // A first: its counted vmcnt leaves the DMAs in flight
      QKVW_DMA(kb + 1, nb);
    }
    QKV_COMPUTE(cur);
    if (kb < 15) QKVA_STAGE(nb);
    __syncthreads();             // drains DMA + ds writes for next step
  }

  // ---- epilogue: Q (wave 0), K (wave 1) natural stores ----
  if (wave < 2) {
#pragma unroll
    for (int a = 0; a < 2; a++)
#pragma unroll
      for (int nt = 0; nt < 4; nt++)
#pragma unroll
        for (int r = 0; r < 4; r++) {
          int row = rt * 32 + a * 16 + quad * 4 + r;    // C/D: row = quad*4+reg, col = l16
          int cm  = nt * 16 + l16;
          qkv[(size_t)wave * QKVSZ + (size_t)row * HD + cm] = f2b(acc[a][nt][r]);
        }
  }

  // ---- epilogue: V (wave 2) -> LDS transpose -> vT[b][h][s] coalesced store ----
  __syncthreads();                                 // LDS free after last MFMA
  {
    unsigned short* Vsh = (unsigned short*)&Ab[0][0];   // 64 h x 48 pitch = 3072 shorts (6 KB)
    if (wave == 2) {
#pragma unroll
      for (int a = 0; a < 2; a++)
#pragma unroll
        for (int nt = 0; nt < 4; nt++)
#pragma unroll
          for (int r = 0; r < 4; r++)
            Vsh[(nt * 16 + l16) * 48 + a * 16 + quad * 4 + r] = f2b(acc[a][nt][r]);
    }
    __syncthreads();
    const int b    = rt >> 6;
    const int seq0 = (rt & 63) * 32;
#pragma unroll
    for (int j = 0; j < 2; j++) {
      int u = t + j * 192;
      if (u < 256) {
        int h  = u >> 2;
        int sq = (u & 3) * 8;
        bf16x8 vv = *(const bf16x8*)(Vsh + h * 48 + sq);
        *(bf16x8*)(qkv + 2 * (size_t)QKVSZ + ((size_t)(b * 64 + h)) * SEQ + seq0 + sq) = vv;
      }
    }
  }
}

// ---------------- Flash attention: 4 waves/block, 64 q-rows, 8-tile split-K chunks --------
// (R8 proven, verbatim)
__global__ __launch_bounds__(256, 4) void attn_split(const unsigned short* __restrict__ qkv,
                                                     float* __restrict__ part,
                                                     float* __restrict__ out) {
  __shared__ __align__(16) unsigned short Kb[2][64 * 64];   // 2 x 8 KB
  __shared__ __align__(16) unsigned short Vb[2][64 * 64];   // 2 x 8 KB, Vt[h][key]
  __shared__ __align__(16) unsigned short Pb[4][16 * 64];   // per-wave P, swizzled

  const int t    = threadIdx.x;
  const int wave = t >> 6;
  const int lane = t & 63;
  const int quad = lane >> 4;
  const int l16  = lane & 15;
  const int B0 = blockIdx.x;        // 64-row q-block
  const int c  = blockIdx.y;        // chunk (8 tiles each)
  const int b  = blockIdx.z;
  const int nch = (B0 >> 3) + 1;    // 1..4
  if (c >= nch) return;
  const int t0 = c * 8;
  const int t1 = min(t0 + 7, B0);
  const int qt = B0 * 4 + wave;
  const int q0 = qt * 16;

  const unsigned short* qg = qkv;
  const unsigned short* kg = qkv + QKVSZ;
  const unsigned short* vg = qkv + 2 * QKVSZ;     // vT[b][h][s]

  const unsigned short* qptr = qg + ((size_t)(b * SEQ + q0 + l16)) * HD + quad * 8;
  const bf16x8 qf0 = *(const bf16x8*)qptr;        // d 0..31
  const bf16x8 qf1 = *(const bf16x8*)(qptr + 32); // d 32..63

  // DMA source offsets (2 instrs per wave per matrix); row = key (K) / head (V)
  int koff[2]; size_t voff[2];
#pragma unroll
  for (int i = 0; i < 2; i++) {
    int u = (wave * 2 + i) * 64 + lane;           // 0..511 16B-units
    int row = u >> 3, k8 = u & 7;
    int swz = (k8 ^ (row & 7)) << 4;
    koff[i] = row * 128 + swz;                          // + kb*8192 within batch plane
    voff[i] = ((size_t)(b * 64 + row) * SEQ) * 2 + swz; // + kb*128
  }
  const char* kgB = (const char*)kg + (size_t)b * SEQ * 128;
  const char* vgB = (const char*)vg;

  f32x4 o0 = {0,0,0,0}, o1 = {0,0,0,0}, o2 = {0,0,0,0}, o3 = {0,0,0,0};
  float mst[4] = {-INFINITY, -INFINITY, -INFINITY, -INFINITY};
  float lst[4] = {0.f, 0.f, 0.f, 0.f};
  const float sc = 0.125f * 1.44269504088896f;    // 1/sqrt(64) * log2(e)

  // prologue: DMA tile t0 -> buf0
#pragma unroll
  for (int i = 0; i < 2; i++) {
    GLOAD_LDS16(kgB + (size_t)t0 * 8192 + koff[i], (char*)&Kb[0][0] + (wave * 2 + i) * 1024);
    GLOAD_LDS16(vgB + voff[i] + (size_t)t0 * 128,  (char*)&Vb[0][0] + (wave * 2 + i) * 1024);
  }
  __syncthreads();

  for (int kb = t0; kb <= t1; kb++) {
    const int cur = (kb - t0) & 1;
    const int nb  = cur ^ 1;

    // issue next tile's DMA (in flight across the whole compute phase)
    if (kb < t1) {
#pragma unroll
      for (int i = 0; i < 2; i++) {
        GLOAD_LDS16(kgB + (size_t)(kb + 1) * 8192 + koff[i], (char*)&Kb[nb][0] + (wave * 2 + i) * 1024);
        GLOAD_LDS16(vgB + voff[i] + (size_t)(kb + 1) * 128,  (char*)&Vb[nb][0] + (wave * 2 + i) * 1024);
      }
    }

    // S = Q K^T  (4 ktiles of 16 keys)
    f32x4 s[4];
#pragma unroll
    for (int kt = 0; kt < 4; kt++) {
      int row = kt * 16 + l16;
      bf16x8 kf0 = *(const bf16x8*)((char*)&Kb[cur][0] + row * 128 + ((quad * 16) ^ ((row & 7) << 4)));
      bf16x8 kf1 = *(const bf16x8*)((char*)&Kb[cur][0] + row * 128 + ((64 + quad * 16) ^ ((row & 7) << 4)));
      f32x4 z = {0.f, 0.f, 0.f, 0.f};
      z = __builtin_amdgcn_mfma_f32_16x16x32_bf16(qf0, kf0, z, 0, 0, 0);
      z = __builtin_amdgcn_mfma_f32_16x16x32_bf16(qf1, kf1, z, 0, 0, 0);
      s[kt] = z;
    }

    // scale; causal mask only on the diagonal tile (kb == B0)
    if (kb == B0) {
#pragma unroll
      for (int r = 0; r < 4; r++) {
        int rowg = q0 + quad * 4 + r;
#pragma unroll
        for (int kt = 0; kt < 4; kt++) {
          int col = kb * 64 + kt * 16 + l16;
          float v = s[kt][r] * sc;
          s[kt][r] = (col > rowg) ? -INFINITY : v;
        }
      }
    } else {
#pragma unroll
      for (int r = 0; r < 4; r++)
#pragma unroll
        for (int kt = 0; kt < 4; kt++) s[kt][r] *= sc;
    }

    // online softmax (reduce across the 16-lane col group)
    float alpha[4];
#pragma unroll
    for (int r = 0; r < 4; r++) {
      float mx = fmaxf(fmaxf(s[0][r], s[1][r]), fmaxf(s[2][r], s[3][r]));
#pragma unroll
      for (int off = 1; off < 16; off <<= 1) mx = fmaxf(mx, __shfl_xor(mx, off, 64));
      float mnew = fmaxf(mst[r], mx);
      alpha[r] = exp2f(mst[r] - mnew);
      mst[r] = mnew;
    }
#pragma unroll
    for (int r = 0; r < 4; r++) {
      float sm = 0.f;
#pragma unroll
      for (int kt = 0; kt < 4; kt++) {
        float p = exp2f(s[kt][r] - mst[r]);
        s[kt][r] = p;
        sm += p;
      }
#pragma unroll
      for (int off = 1; off < 16; off <<= 1) sm += __shfl_xor(sm, off, 64);
      lst[r] = lst[r] * alpha[r] + sm;
    }
#pragma unroll
    for (int r = 0; r < 4; r++) { o0[r] *= alpha[r]; o1[r] *= alpha[r]; o2[r] *= alpha[r]; o3[r] *= alpha[r]; }

    // P (C-layout) -> per-wave LDS bf16 (swizzled); wave-local dep, no barrier needed
#pragma unroll
    for (int kt = 0; kt < 4; kt++)
#pragma unroll
      for (int r = 0; r < 4; r++) {
        int row = quad * 4 + r;
        *(unsigned short*)((char*)&Pb[wave][0] + row * 128 +
                           ((kt * 32 + l16 * 2) ^ ((row & 7) << 4))) = f2b(s[kt][r]);
      }

    // O += P V
#pragma unroll
    for (int kc = 0; kc < 2; kc++) {
      bf16x8 pf = *(const bf16x8*)((char*)&Pb[wave][0] + l16 * 128 +
                                   ((kc * 64 + quad * 16) ^ ((l16 & 7) << 4)));
      int r0 = l16, r1 = 16 + l16, r2 = 32 + l16, r3 = 48 + l16;
      bf16x8 vf0 = *(const bf16x8*)((char*)&Vb[cur][0] + r0 * 128 + ((kc * 64 + quad * 16) ^ ((r0 & 7) << 4)));
      bf16x8 vf1 = *(const bf16x8*)((char*)&Vb[cur][0] + r1 * 128 + ((kc * 64 + quad * 16) ^ ((r1 & 7) << 4)));
      bf16x8 vf2 = *(const bf16x8*)((char*)&Vb[cur][0] + r2 * 128 + ((kc * 64 + quad * 16) ^ ((r2 & 7) << 4)));
      bf16x8 vf3 = *(const bf16x8*)((char*)&Vb[cur][0] + r3 * 128 + ((kc * 64 + quad * 16) ^ ((r3 & 7) << 4)));
      o0 = __builtin_amdgcn_mfma_f32_16x16x32_bf16(pf, vf0, o0, 0, 0, 0);
      o1 = __builtin_amdgcn_mfma_f32_16x16x32_bf16(pf, vf1, o1, 0, 0, 0);
      o2 = __builtin_amdgcn_mfma_f32_16x16x32_bf16(pf, vf2, o2, 0, 0, 0);
      o3 = __builtin_amdgcn_mfma_f32_16x16x32_bf16(pf, vf3, o3, 0, 0, 0);
    }

    __syncthreads();   // drains next-tile DMA; buffers swap
  }

  if (nch == 1) {  // B0 < 8: single chunk, finalize directly
#pragma unroll
    for (int r = 0; r < 4; r++) {
      float inv = 1.f / lst[r];
      int rowg = q0 + quad * 4 + r;
      size_t ob = ((size_t)(b * SEQ + rowg)) * HD + l16;
      out[ob + 0]  = o0[r] * inv;
      out[ob + 16] = o1[r] * inv;
      out[ob + 32] = o2[r] * inv;
      out[ob + 48] = o3[r] * inv;
    }
  } else {         // write unnormalized partial + (m,l); row in [0,64) within qblock
    float* ps = part + ((size_t)((b * 32 + B0) * 4 + c)) * PSLOT2;
#pragma unroll
    for (int r = 0; r < 4; r++) {
      int row = wave * 16 + quad * 4 + r;
      ps[row * 64 + 0  + l16] = o0[r];
      ps[row * 64 + 16 + l16] = o1[r];
      ps[row * 64 + 32 + l16] = o2[r];
      ps[row * 64 + 48 + l16] = o3[r];
      if (l16 == 0) {
        ps[4096 + row] = mst[r];
        ps[4160 + row] = lst[r];
      }
    }
  }
}

// ---------------- merge nch partials per 64-row q-block ----------------
// (R8 proven, verbatim)
__global__ __launch_bounds__(256) void attn_merge(const float* __restrict__ part,
                                                  float* __restrict__ out) {
  const int bx = blockIdx.x;
  const int B0 = 8 + (bx >> 2);
  const int rg = bx & 3;
  const int b  = blockIdx.y;
  const int nch = (B0 >> 3) + 1;    // 2..4
  const int t  = threadIdx.x;
  const int h  = t & 63;
  const int rloc = t >> 6;          // 0..3
  const float* base = part + ((size_t)((b * 32 + B0) * 4)) * PSLOT2;
#pragma unroll
  for (int i = 0; i < 4; i++) {
    int row = rg * 16 + rloc * 4 + i;
    float mv[4], lv[4], ov[4];
#pragma unroll
    for (int cc = 0; cc < 4; cc++) {
      int cs = (cc < nch) ? cc : 0;                 // clamp: valid address, masked later
      const float* ps = base + (size_t)cs * PSLOT2;
      mv[cc] = ps[4096 + row];
      lv[cc] = ps[4160 + row];
      ov[cc] = ps[row * 64 + h];
    }
    float M = -INFINITY;
#pragma unroll
    for (int cc = 0; cc < 4; cc++) M = fmaxf(M, (cc < nch) ? mv[cc] : -INFINITY);
    float L = 0.f, o = 0.f;
#pragma unroll
    for (int cc = 0; cc < 4; cc++) {
      float e = (cc < nch) ? exp2f(mv[cc] - M) : 0.f;
      L += lv[cc] * e;
      o += ov[cc] * e;
    }
    out[((size_t)(b * SEQ + B0 * 64 + row)) * HD + h] = o / L;
  }
}

extern "C" void kernel_launch(void* const* d_in, const int* in_sizes, int n_in,
                              void* d_out, int out_size, void* d_ws, size_t ws_size,
                              hipStream_t stream) {
  const float* emb = (const float*)d_in[0];
  const float* wq  = (const float*)d_in[1];
  const float* wk  = (const float*)d_in[2];
  const float* wv  = (const float*)d_in[3];
  unsigned short* ws  = (unsigned short*)d_ws;
  unsigned short* wt  = ws;              // 196608 bf16
  unsigned short* qkv = ws + WTSZ;       // q,k natural + vT  (3 x 1048576 bf16)
  float* part = (float*)(ws + WTSZ + 3 * QKVSZ);   // 32*4*8 slots x 4224 fp32 = 17.3 MB

  hipLaunchKernelGGL(wtrans_kernel,   dim3(WTSZ / 256), dim3(256), 0, stream, wq, wk, wv, wt);
  hipLaunchKernelGGL(qkv_proj_kernel, dim3(512),        dim3(192), 0, stream, emb, wt, qkv);
  hipLaunchKernelGGL(attn_split,      dim3(32, 4, 8),   dim3(256), 0, stream, qkv, part, (float*)d_out);
  hipLaunchKernelGGL(attn_merge,      dim3(96, 8),      dim3(256), 0, stream, part, (float*)d_out);
}